// Round 1
// baseline (138.251 us; speedup 1.0000x reference)
//
#include <hip/hip_runtime.h>

namespace {
constexpr int kN   = 2048;
constexpr int kT   = 64;
constexpr int kDH  = 32;
constexpr int kDE  = 64;
constexpr int kSUB = 16;
constexpr int kCUT = 24;    // CUM[1]
constexpr int kAPB = 4;     // atoms per block (one per wave)
constexpr float kRcs = 0.3f;
constexpr float kRc  = 0.6f;
constexpr float kPi  = 3.14159265358979323846f;
}

// D[e][f] = sum_a Q[a][e] * Q[a][f], where
// Q[a][e] = sum_t r_tilde[t][a] * G[t][e]
//         = sum_k sum_{hi<=32} P[k][hi][a] * W2x[ty+k][hi][e]
// with P[k][hi][a] = sum_{t in block k} r_tilde[t][a] * hx[t][hi],
// hx[t][hi<32] = relu(s_t*W1+b1), hx[t][32] = 1, W2x[:,32,:] = b2 (bias fold).
__global__ __launch_bounds__(256, 2)
void descriptor_kernel(const float* __restrict__ pos,    // (S,N,3)
                       const float* __restrict__ W1,     // (3,1,32)
                       const float* __restrict__ b1,     // (3,32)
                       const float* __restrict__ W2,     // (3,32,64)
                       const float* __restrict__ b2,     // (3,64)
                       const int*   __restrict__ types,  // (1,N)
                       const int*   __restrict__ neigh,  // (S,N,T)
                       float*       __restrict__ out)    // (S,N,64,16)
{
    __shared__ float sW2x[3][kDH + 1][kDE];       // row kDH holds b2
    __shared__ float sW1[3][kDH];
    __shared__ float sB1[3][kDH];
    __shared__ float sRT[kAPB][kT][4];            // r_tilde per atom
    __shared__ float sHx[kAPB][kDH + 1][kT + 1];  // +1 pad: column reads conflict-free
    __shared__ float sP[kAPB][2][kDH + 1][4];
    __shared__ float sQ[kAPB][kDE][4];

    const int tid = threadIdx.x;
    const int w = tid >> 6;   // wave id == atom slot
    const int q = tid & 63;

    // ---- stage weights ----
    for (int i = tid; i < 3 * kDH * kDE; i += 256) {
        const int net = i >> 11;          // / (32*64)
        const int r = i & 2047;
        sW2x[net][r >> 6][r & 63] = W2[i];
    }
    if (tid < 3 * kDE) sW2x[tid / kDE][kDH][tid % kDE] = b2[tid];
    if (tid < 3 * kDH) {
        sW1[tid / kDH][tid % kDH] = W1[tid];
        sB1[tid / kDH][tid % kDH] = b1[tid];
    }

    const int atom = blockIdx.x * kAPB + w;   // flat s*N + n
    const int sidx = atom >> 11;              // N == 2048
    const int n = atom & (kN - 1);
    const int ty = types[n];                  // PAIR_IDX[ty] = {ty, ty+1}

    __syncthreads();

    // ---- phase 1: gather neighbor, PBC, switching fn, r_tilde, h ----
    {
        const int t = q;
        const int j = neigh[(size_t)atom * kT + t];
        const float* pn = pos + (size_t)atom * 3;
        const float* pj = pos + ((size_t)sidx * kN + j) * 3;
        float dx = pj[0] - pn[0]; dx -= rintf(dx);
        float dy = pj[1] - pn[1]; dy -= rintf(dy);
        float dz = pj[2] - pn[2]; dz -= rintf(dz);
        float dist = sqrtf(dx * dx + dy * dy + dz * dz);
        dist = fmaxf(dist, 1e-12f);
        const float u = (dist - kRcs) * (1.0f / (kRc - kRcs));
        const float sw = 0.5f * __cosf(kPi * u) + 0.5f;
        const float factor = (dist < kRcs) ? 1.0f : ((dist < kRc) ? sw : 0.0f);
        const float sv = factor / dist;
        const float inv = sv / dist;
        sRT[w][t][0] = sv;
        sRT[w][t][1] = dx * inv;
        sRT[w][t][2] = dy * inv;
        sRT[w][t][3] = dz * inv;
        const int it = ty + (t >= kCUT ? 1 : 0);
        #pragma unroll
        for (int hi = 0; hi < kDH; ++hi) {
            const float h = fmaf(sv, sW1[it][hi], sB1[it][hi]);
            sHx[w][hi][t] = fmaxf(h, 0.0f);
        }
        sHx[w][kDH][t] = 1.0f;   // bias row
    }
    __syncthreads();

    // ---- phase 2: P[k][hi][a] = sum_t rt[t][a] * hx[hi][t] ----
    if (q <= kDH) {
        const int hi = q;
        float a0 = 0.f, a1 = 0.f, a2 = 0.f, a3 = 0.f;
        float c0 = 0.f, c1 = 0.f, c2 = 0.f, c3 = 0.f;
        #pragma unroll 8
        for (int t = 0; t < kCUT; ++t) {
            const float hv = sHx[w][hi][t];
            const float4 rt = *(const float4*)&sRT[w][t][0];
            a0 = fmaf(rt.x, hv, a0);
            a1 = fmaf(rt.y, hv, a1);
            a2 = fmaf(rt.z, hv, a2);
            a3 = fmaf(rt.w, hv, a3);
        }
        #pragma unroll 8
        for (int t = kCUT; t < kT; ++t) {
            const float hv = sHx[w][hi][t];
            const float4 rt = *(const float4*)&sRT[w][t][0];
            c0 = fmaf(rt.x, hv, c0);
            c1 = fmaf(rt.y, hv, c1);
            c2 = fmaf(rt.z, hv, c2);
            c3 = fmaf(rt.w, hv, c3);
        }
        *(float4*)&sP[w][0][hi][0] = make_float4(a0, a1, a2, a3);
        *(float4*)&sP[w][1][hi][0] = make_float4(c0, c1, c2, c3);
    }
    __syncthreads();

    // ---- phase 3: Q[e][a] = sum_k sum_hi P[k][hi][a] * W2x[ty+k][hi][e] ----
    {
        const int e = q;
        float q0 = 0.f, q1 = 0.f, q2 = 0.f, q3 = 0.f;
        #pragma unroll
        for (int k = 0; k < 2; ++k) {
            const float (*w2n)[kDE] = sW2x[ty + k];
            #pragma unroll
            for (int hi = 0; hi <= kDH; ++hi) {
                const float wv = w2n[hi][e];          // stride-1 across lanes
                const float4 p = *(const float4*)&sP[w][k][hi][0];  // broadcast
                q0 = fmaf(p.x, wv, q0);
                q1 = fmaf(p.y, wv, q1);
                q2 = fmaf(p.z, wv, q2);
                q3 = fmaf(p.w, wv, q3);
            }
        }
        *(float4*)&sQ[w][e][0] = make_float4(q0, q1, q2, q3);
    }
    __syncthreads();

    // ---- phase 4: D[e][f] = sum_a Q[e][a]*Q[f][a]; coalesced store ----
    {
        const int e = q;
        const float4 qe = *(const float4*)&sQ[w][e][0];
        float4* op = (float4*)(out + ((size_t)atom * kDE + e) * kSUB);
        #pragma unroll
        for (int fq = 0; fq < 4; ++fq) {
            float rr[4];
            #pragma unroll
            for (int m = 0; m < 4; ++m) {
                const float4 qf = *(const float4*)&sQ[w][fq * 4 + m][0];  // broadcast
                rr[m] = qe.x * qf.x + qe.y * qf.y + qe.z * qf.z + qe.w * qf.w;
            }
            op[fq] = make_float4(rr[0], rr[1], rr[2], rr[3]);
        }
    }
}

extern "C" void kernel_launch(void* const* d_in, const int* in_sizes, int n_in,
                              void* d_out, int out_size, void* d_ws, size_t ws_size,
                              hipStream_t stream)
{
    (void)in_sizes; (void)n_in; (void)out_size; (void)d_ws; (void)ws_size;
    const float* pos   = (const float*)d_in[0];
    const float* W1    = (const float*)d_in[1];
    const float* b1    = (const float*)d_in[2];
    const float* W2    = (const float*)d_in[3];
    const float* b2    = (const float*)d_in[4];
    const int*   types = (const int*)d_in[5];
    const int*   neigh = (const int*)d_in[6];
    float* out = (float*)d_out;

    const int total_atoms = 8 * kN;           // S*N = 16384
    dim3 grid(total_atoms / kAPB), block(256);
    hipLaunchKernelGGL(descriptor_kernel, grid, block, 0, stream,
                       pos, W1, b1, W2, b2, types, neigh, out);
}

// Round 2
// 120.588 us; speedup vs baseline: 1.1465x; 1.1465x over previous
//
#include <hip/hip_runtime.h>

namespace {
constexpr int kN   = 2048;
constexpr int kT   = 64;
constexpr int kDH  = 32;
constexpr int kDE  = 64;
constexpr int kSUB = 16;
constexpr int kCUT = 24;    // CUM[1]
constexpr int kAPB = 8;     // atoms per block (one per wave), 512 threads
constexpr float kRcs = 0.3f;
constexpr float kRc  = 0.6f;
constexpr float kPi  = 3.14159265358979323846f;
}

// D[e][f] = sum_a Q[a][e] * Q[a][f], where
// Q[a][e] = sum_k sum_{hi<=32} P[k][hi][a] * W2x[ty+k][hi][e]
// with P[k][hi][a] = sum_{t in block k} r_tilde[t][a] * h[t][hi],
// h[t][hi<32] = relu(s_t*W1+b1) recomputed in-register (no sHx transpose),
// h[t][32] = 1, W2x[:,32,:] = b2 (bias fold).
__global__ __launch_bounds__(512, 6)
void descriptor_kernel(const float* __restrict__ pos,    // (S,N,3)
                       const float* __restrict__ W1,     // (3,1,32)
                       const float* __restrict__ b1,     // (3,32)
                       const float* __restrict__ W2,     // (3,32,64)
                       const float* __restrict__ b2,     // (3,64)
                       const int*   __restrict__ types,  // (1,N)
                       const int*   __restrict__ neigh,  // (S,N,T)
                       float*       __restrict__ out)    // (S,N,64,16)
{
    __shared__ float sW2x[3][kDH + 1][kDE];      // 25344 B, row kDH holds b2
    __shared__ float sW1[3][kDH];                // 384 B
    __shared__ float sB1[3][kDH];                // 384 B
    __shared__ float sRT[kAPB][kT][4];           // 8192 B: r_tilde per atom
    __shared__ float sP[kAPB][2][kDH + 1][4];    // 8448 B
    __shared__ float sQ[kAPB][kDE][4];           // 8192 B   => 50944 B total

    const int tid = threadIdx.x;
    const int w = tid >> 6;   // wave id == atom slot
    const int q = tid & 63;

    // ---- stage weights (independent of phase 1) ----
    for (int i = tid; i < 3 * kDH * kDE; i += 512) {
        const int net = i >> 11;          // / (32*64)
        const int r = i & 2047;
        sW2x[net][r >> 6][r & 63] = W2[i];
    }
    if (tid < 3 * kDE) sW2x[tid / kDE][kDH][tid % kDE] = b2[tid];
    if (tid < 3 * kDH) {
        sW1[tid / kDH][tid % kDH] = W1[tid];
        sB1[tid / kDH][tid % kDH] = b1[tid];
    }

    const int atom = blockIdx.x * kAPB + w;   // flat s*N + n
    const int sidx = atom >> 11;              // N == 2048
    const int n = atom & (kN - 1);
    const int ty = types[n];                  // PAIR_IDX[ty] = {ty, ty+1}

    // ---- phase 1: gather neighbor, PBC, switching fn, r_tilde (lane = t) ----
    {
        const int t = q;
        const int j = neigh[(size_t)atom * kT + t];
        const float* pn = pos + (size_t)atom * 3;          // wave-uniform
        const float* pj = pos + ((size_t)sidx * kN + j) * 3;
        float dx = pj[0] - pn[0]; dx -= rintf(dx);
        float dy = pj[1] - pn[1]; dy -= rintf(dy);
        float dz = pj[2] - pn[2]; dz -= rintf(dz);
        float dist = sqrtf(dx * dx + dy * dy + dz * dz);
        dist = fmaxf(dist, 1e-12f);
        const float u = (dist - kRcs) * (1.0f / (kRc - kRcs));
        const float sw = 0.5f * __cosf(kPi * u) + 0.5f;
        const float factor = (dist < kRcs) ? 1.0f : ((dist < kRc) ? sw : 0.0f);
        const float sv = factor / dist;
        const float inv = sv / dist;
        *(float4*)&sRT[w][t][0] = make_float4(sv, dx * inv, dy * inv, dz * inv);
    }
    __syncthreads();

    // ---- phase 2: P[k][hi][a] = sum_t rt[t][a] * relu(s_t*w1+b1)  (lane = hi) ----
    if (q <= kDH) {
        const int hi = q;
        const bool bias = (hi == kDH);
        const int hc = bias ? 0 : hi;
        const float w10 = bias ? 0.0f : sW1[ty][hc];
        const float b10 = bias ? 1.0f : sB1[ty][hc];
        const float w11 = bias ? 0.0f : sW1[ty + 1][hc];
        const float b11 = bias ? 1.0f : sB1[ty + 1][hc];
        float a0 = 0.f, a1 = 0.f, a2 = 0.f, a3 = 0.f;
        float c0 = 0.f, c1 = 0.f, c2 = 0.f, c3 = 0.f;
        #pragma unroll 8
        for (int t = 0; t < kCUT; ++t) {
            const float4 rt = *(const float4*)&sRT[w][t][0];   // broadcast
            const float hv = fmaxf(fmaf(rt.x, w10, b10), 0.0f);
            a0 = fmaf(rt.x, hv, a0);
            a1 = fmaf(rt.y, hv, a1);
            a2 = fmaf(rt.z, hv, a2);
            a3 = fmaf(rt.w, hv, a3);
        }
        #pragma unroll 8
        for (int t = kCUT; t < kT; ++t) {
            const float4 rt = *(const float4*)&sRT[w][t][0];   // broadcast
            const float hv = fmaxf(fmaf(rt.x, w11, b11), 0.0f);
            c0 = fmaf(rt.x, hv, c0);
            c1 = fmaf(rt.y, hv, c1);
            c2 = fmaf(rt.z, hv, c2);
            c3 = fmaf(rt.w, hv, c3);
        }
        *(float4*)&sP[w][0][hi][0] = make_float4(a0, a1, a2, a3);
        *(float4*)&sP[w][1][hi][0] = make_float4(c0, c1, c2, c3);
    }
    __syncthreads();

    // ---- phase 3: Q[e][a] = sum_k sum_hi P[k][hi][a] * W2x[ty+k][hi][e] (lane = e) ----
    {
        const int e = q;
        float q0 = 0.f, q1 = 0.f, q2 = 0.f, q3 = 0.f;
        #pragma unroll
        for (int k = 0; k < 2; ++k) {
            const float (*w2n)[kDE] = sW2x[ty + k];
            #pragma unroll
            for (int hi = 0; hi <= kDH; ++hi) {
                const float wv = w2n[hi][e];                        // stride-1 lanes
                const float4 p = *(const float4*)&sP[w][k][hi][0];  // broadcast
                q0 = fmaf(p.x, wv, q0);
                q1 = fmaf(p.y, wv, q1);
                q2 = fmaf(p.z, wv, q2);
                q3 = fmaf(p.w, wv, q3);
            }
        }
        *(float4*)&sQ[w][e][0] = make_float4(q0, q1, q2, q3);
    }
    __syncthreads();

    // ---- phase 4: D[e][f] = sum_a Q[e][a]*Q[f][a]; coalesced float4 store ----
    {
        const int e = q;
        const float4 qe = *(const float4*)&sQ[w][e][0];
        float4* op = (float4*)(out + ((size_t)atom * kDE + e) * kSUB);
        #pragma unroll
        for (int fq = 0; fq < 4; ++fq) {
            float rr[4];
            #pragma unroll
            for (int m = 0; m < 4; ++m) {
                const float4 qf = *(const float4*)&sQ[w][fq * 4 + m][0];  // broadcast
                rr[m] = qe.x * qf.x + qe.y * qf.y + qe.z * qf.z + qe.w * qf.w;
            }
            op[fq] = make_float4(rr[0], rr[1], rr[2], rr[3]);
        }
    }
}

extern "C" void kernel_launch(void* const* d_in, const int* in_sizes, int n_in,
                              void* d_out, int out_size, void* d_ws, size_t ws_size,
                              hipStream_t stream)
{
    (void)in_sizes; (void)n_in; (void)out_size; (void)d_ws; (void)ws_size;
    const float* pos   = (const float*)d_in[0];
    const float* W1    = (const float*)d_in[1];
    const float* b1    = (const float*)d_in[2];
    const float* W2    = (const float*)d_in[3];
    const float* b2    = (const float*)d_in[4];
    const int*   types = (const int*)d_in[5];
    const int*   neigh = (const int*)d_in[6];
    float* out = (float*)d_out;

    const int total_atoms = 8 * kN;           // S*N = 16384
    dim3 grid(total_atoms / kAPB), block(512);
    hipLaunchKernelGGL(descriptor_kernel, grid, block, 0, stream,
                       pos, W1, b1, W2, b2, types, neigh, out);
}